// Round 6
// baseline (104.129 us; speedup 1.0000x reference)
//
#include <hip/hip_runtime.h>

#define NN      4096   // total nodes
#define BG      64     // graphs
#define NPG_    64     // nodes per graph
#define LT_     128
#define LL_     32
#define D_      256
#define OUT_    1024
#define NPBF    2      // nodes per block (fused kernel)

// ---------------- Fused gather + projection ----------------
// 2048 blocks x 256 thr, 2 nodes/block -> 8 blocks/CU (100% wave occupancy).
// Phases: ids->LDS; 4-way wave-split ragged gathers -> LDS reduce -> xT/xL;
// k-split proj (wave w owns k in [64w,64w+64)), lane owns 4 cols x 2 nodes;
// LDS k-reduce, relu, w_adap combine, coalesced write. Fixed-order reductions.
__global__ __launch_bounds__(256, 8) void fused_kernel(
    const int*   __restrict__ text_ids,
    const int*   __restrict__ label_ids,
    const int*   __restrict__ text_len,
    const int*   __restrict__ label_len,
    const float* __restrict__ word_emb,
    const float* __restrict__ label_emb,
    const float* __restrict__ Wg_text,
    const float* __restrict__ Wg_label,
    const float* __restrict__ w_adap,
    float*       __restrict__ h_comb)     // [NN, D]
{
    __shared__ int   sIds[NPBF][LT_ + LL_];   // 1.25 KB
    __shared__ float red[4][NPBF * D_];       // 8 KB, time-multiplexed
    __shared__ float xT[NPBF][D_ + 8];        // 2.06 KB
    __shared__ float xL[NPBF][D_ + 8];        // 2.06 KB

    const int tid  = threadIdx.x;
    const int wave = tid >> 6;
    const int lane = tid & 63;
    const int base = blockIdx.x * NPBF;

    // ---- Phase 1: stage ids (coalesced, one shot) ----
    {
        const int nd = tid >> 7, t = tid & (LT_ - 1);      // 256 = NPBF*LT_
        sIds[nd][t] = text_ids[(size_t)(base + nd) * LT_ + t];
    }
    if (tid < NPBF * LL_) {
        const int nd = tid >> 5, t = tid & (LL_ - 1);
        sIds[nd][LT_ + t] = label_ids[(size_t)(base + nd) * LL_ + t];
    }
    int lt[NPBF], ll[NPBF];
    #pragma unroll
    for (int nd = 0; nd < NPBF; ++nd) {
        lt[nd] = text_len[base + nd];
        ll[nd] = label_len[base + nd];
    }
    __syncthreads();

    // ---- Phase 2: ragged gathers (wave w takes rows l = w, w+4, ...) ----
    float4 aT[NPBF], aL[NPBF];
    {
        const float* __restrict__ bp = word_emb + (size_t)lane * 4;
        #pragma unroll
        for (int nd = 0; nd < NPBF; ++nd) {
            float4 a = make_float4(0.f, 0.f, 0.f, 0.f);
            #pragma unroll 8
            for (int l = wave; l < lt[nd]; l += 4) {
                const float4 v = *reinterpret_cast<const float4*>(
                    bp + (size_t)sIds[nd][l] * D_);
                a.x += v.x; a.y += v.y; a.z += v.z; a.w += v.w;
            }
            aT[nd] = a;
        }
    }
    {
        const float* __restrict__ bp = label_emb + (size_t)lane * 4;
        #pragma unroll
        for (int nd = 0; nd < NPBF; ++nd) {
            float4 a = make_float4(0.f, 0.f, 0.f, 0.f);
            #pragma unroll 8
            for (int l = wave; l < ll[nd]; l += 4) {
                const float4 v = *reinterpret_cast<const float4*>(
                    bp + (size_t)sIds[nd][LT_ + l] * D_);
                a.x += v.x; a.y += v.y; a.z += v.z; a.w += v.w;
            }
            aL[nd] = a;
        }
    }

    // text cross-wave reduce -> xT (divide by len here)
    #pragma unroll
    for (int nd = 0; nd < NPBF; ++nd)
        *reinterpret_cast<float4*>(&red[wave][nd * D_ + lane * 4]) = aT[nd];
    __syncthreads();
    #pragma unroll
    for (int i = 0; i < NPBF; ++i) {
        const int idx = tid + 256 * i;          // nd = i, col = tid
        const float v = (red[0][idx] + red[1][idx]) + (red[2][idx] + red[3][idx]);
        xT[i][tid] = v / (float)lt[i];
    }
    __syncthreads();
    // label cross-wave reduce -> xL (reuse red)
    #pragma unroll
    for (int nd = 0; nd < NPBF; ++nd)
        *reinterpret_cast<float4*>(&red[wave][nd * D_ + lane * 4]) = aL[nd];
    __syncthreads();
    #pragma unroll
    for (int i = 0; i < NPBF; ++i) {
        const int idx = tid + 256 * i;
        xL[i][tid] = (red[0][idx] + red[1][idx]) + (red[2][idx] + red[3][idx]);
    }
    __syncthreads();

    // ---- Phase 3: k-split projection ----
    float pT[NPBF][4], pL[NPBF][4];
    #pragma unroll
    for (int nd = 0; nd < NPBF; ++nd) {
        #pragma unroll
        for (int j = 0; j < 4; ++j) { pT[nd][j] = 0.f; pL[nd][j] = 0.f; }
    }
    const int c0 = lane * 4;
    const int k0 = wave * 64;

    for (int k4 = 0; k4 < 64; k4 += 4) {
        const int k = k0 + k4;
        float xt[NPBF][4], xl[NPBF][4];
        #pragma unroll
        for (int nd = 0; nd < NPBF; ++nd) {
            const float4 a = *reinterpret_cast<const float4*>(&xT[nd][k]);
            const float4 b = *reinterpret_cast<const float4*>(&xL[nd][k]);
            xt[nd][0] = a.x; xt[nd][1] = a.y; xt[nd][2] = a.z; xt[nd][3] = a.w;
            xl[nd][0] = b.x; xl[nd][1] = b.y; xl[nd][2] = b.z; xl[nd][3] = b.w;
        }
        #pragma unroll
        for (int dk = 0; dk < 4; ++dk) {
            const size_t ro = (size_t)(k + dk) * D_ + c0;
            const float4 wt = *reinterpret_cast<const float4*>(Wg_text  + ro);
            const float4 wl = *reinterpret_cast<const float4*>(Wg_label + ro);
            #pragma unroll
            for (int nd = 0; nd < NPBF; ++nd) {
                const float xv = xt[nd][dk];
                pT[nd][0] = fmaf(xv, wt.x, pT[nd][0]);
                pT[nd][1] = fmaf(xv, wt.y, pT[nd][1]);
                pT[nd][2] = fmaf(xv, wt.z, pT[nd][2]);
                pT[nd][3] = fmaf(xv, wt.w, pT[nd][3]);
                const float yv = xl[nd][dk];
                pL[nd][0] = fmaf(yv, wl.x, pL[nd][0]);
                pL[nd][1] = fmaf(yv, wl.y, pL[nd][1]);
                pL[nd][2] = fmaf(yv, wl.z, pL[nd][2]);
                pL[nd][3] = fmaf(yv, wl.w, pL[nd][3]);
            }
        }
    }

    // ---- Phase 4: k-reduction + combine (fixed order) ----
    #pragma unroll
    for (int nd = 0; nd < NPBF; ++nd)
        *reinterpret_cast<float4*>(&red[wave][nd * D_ + c0]) =
            make_float4(pT[nd][0], pT[nd][1], pT[nd][2], pT[nd][3]);
    __syncthreads();
    float rT[NPBF];
    #pragma unroll
    for (int i = 0; i < NPBF; ++i) {
        const int idx = tid + 256 * i;
        rT[i] = (red[0][idx] + red[1][idx]) + (red[2][idx] + red[3][idx]);
    }
    __syncthreads();
    #pragma unroll
    for (int nd = 0; nd < NPBF; ++nd)
        *reinterpret_cast<float4*>(&red[wave][nd * D_ + c0]) =
            make_float4(pL[nd][0], pL[nd][1], pL[nd][2], pL[nd][3]);
    __syncthreads();

    const float w0 = w_adap[0] * (1.0f / (float)NPG_);
    const float w1 = w_adap[1] * (1.0f / (float)NPG_);
    #pragma unroll
    for (int i = 0; i < NPBF; ++i) {
        const int idx = tid + 256 * i;
        const float rL = (red[0][idx] + red[1][idx]) + (red[2][idx] + red[3][idx]);
        const float ht = rT[i] > 0.f ? rT[i] : 0.f;
        const float hl = rL    > 0.f ? rL    : 0.f;
        h_comb[(size_t)(base + i) * D_ + tid] = w0 * ht + w1 * hl;
    }
}

// ---------------- Kernel C: per-graph readout + MLP, 4 blocks per graph split Wout ----------------
__global__ __launch_bounds__(256) void graph_kernel(
    const float* __restrict__ h_comb,   // [NN, D]
    const float* __restrict__ W1,       // [D, D]
    const float* __restrict__ b1,       // [D]
    const float* __restrict__ Wout,     // [D, OUT]
    const float* __restrict__ bout,     // [OUT]
    float*       __restrict__ out)      // [BG, OUT]
{
    __shared__ float fused[D_];
    __shared__ float hrow[D_];

    const int bx   = blockIdx.x;
    const int b    = bx >> 2;
    const int part = bx & 3;
    const int tid  = threadIdx.x;

    float acc = 0.f;
    const float* __restrict__ basep = h_comb + (size_t)b * NPG_ * D_ + tid;
    #pragma unroll 8
    for (int n = 0; n < NPG_; ++n) acc += basep[(size_t)n * D_];
    fused[tid] = acc;
    __syncthreads();

    float a1 = b1[tid];
    for (int d = 0; d < D_; ++d)
        a1 = fmaf(fused[d], W1[(size_t)d * D_ + tid], a1);
    hrow[tid] = a1 > 0.f ? a1 : 0.f;
    __syncthreads();

    const int j = part * 256 + tid;
    float o = bout[j];
    for (int d = 0; d < D_; ++d)
        o = fmaf(hrow[d], Wout[(size_t)d * OUT_ + j], o);
    out[(size_t)b * OUT_ + j] = o;
}

extern "C" void kernel_launch(void* const* d_in, const int* in_sizes, int n_in,
                              void* d_out, int out_size, void* d_ws, size_t ws_size,
                              hipStream_t stream) {
    const int*   text_ids  = (const int*)  d_in[0];
    const int*   label_ids = (const int*)  d_in[1];
    const int*   text_len  = (const int*)  d_in[2];
    const int*   label_len = (const int*)  d_in[3];
    const float* word_emb  = (const float*)d_in[4];
    const float* label_emb = (const float*)d_in[5];
    const float* Wg_text   = (const float*)d_in[6];
    const float* Wg_label  = (const float*)d_in[7];
    const float* w_adap    = (const float*)d_in[8];
    const float* W1        = (const float*)d_in[9];
    const float* b1        = (const float*)d_in[10];
    const float* Wout      = (const float*)d_in[11];
    const float* bout      = (const float*)d_in[12];

    float* h_comb = (float*)d_ws;      // 4 MiB scratch
    float* out    = (float*)d_out;

    fused_kernel<<<NN / NPBF, 256, 0, stream>>>(
        text_ids, label_ids, text_len, label_len,
        word_emb, label_emb, Wg_text, Wg_label, w_adap, h_comb);

    graph_kernel<<<BG * 4, 256, 0, stream>>>(
        h_comb, W1, b1, Wout, bout, out);
}